// Round 14
// baseline (55.076 us; speedup 1.0000x reference)
//
#include <hip/hip_runtime.h>
#include <math.h>

typedef __attribute__((ext_vector_type(8))) short short8;
typedef __attribute__((ext_vector_type(4))) float f32x4;

#define BB 8192      // batch
#define CC 1000      // classes
#define NN 9192      // B + C real columns
#define NPAD 9216    // padded
#define DD 128       // feature dim
#define RBW 64       // rows per WAVE (block covers 4*64 = 256 rows)
#define NSPLIT 16    // column splits (blockIdx.y) -> grid 32x16 = 512 = 2 blocks/CU
#define CPW 576      // columns per block/wave = 9216/NSPLIT
#define NT 36        // 16-col chunks (divisible by 3 for 3-buffer rotation)
#define K2F 14.426950408889634f   // (1/T) * log2(e)

// ---- workspace layout (float offsets) ----
#define WS_CLS   0        // [1024] int batch histogram
#define WS_TCOL  1024     // [9216] int per-column class
#define WS_RCP0  10240    // [9216] 1/cnt
#define WS_RCP1  19456    // [9216] 1/(cnt-1)
#define WS_SPART 28672    // [16*8192]
#define WS_PPART 159744   // [16*8192]
#define WS_F2    290816   // fragment-major bf16 [9216*128]

static __device__ __forceinline__ unsigned short f2bf(float x) {
    unsigned int b = __float_as_uint(x);
    unsigned int r = (b + 0x7FFFu + ((b >> 16) & 1u)) >> 16;   // RNE
    return (unsigned short)r;
}
static __device__ __forceinline__ float fexp2(float x) {
    float r; asm("v_exp_f32 %0, %1" : "=v"(r) : "v"(x)); return r;
}
static __device__ __forceinline__ float flog2(float x) {
    float r; asm("v_log_f32 %0, %1" : "=v"(r) : "v"(x)); return r;
}

// ---- fused prep: blocks 0..143 convert fp32 -> fragment-major bf16;
//      block 144: histogram + per-column class/weight tables ----
__global__ __launch_bounds__(1024) void prep_kernel(
    const float* __restrict__ feats, const float* __restrict__ ctrs,
    const int* __restrict__ tgt, unsigned short* __restrict__ F2,
    int* __restrict__ cls, int* __restrict__ tcol,
    float* __restrict__ rcp0, float* __restrict__ rcp1)
{
    const int tid = threadIdx.x;
    if (blockIdx.x < 144) {
        // cvt: one short8-unit per thread.  F2 fragment-major: 16B unit
        // u = (j16*4 + ks)*64 + l4*16 + l15 holds (col j=j16*16+l15, k=ks*32+l4*8..+8)
        int u = blockIdx.x * 1024 + tid;          // < 147456 = NPAD*16
        int j = u >> 4, quad = u & 15;
        int k0 = quad * 8;
        float4 v0 = {0.f,0.f,0.f,0.f}, v1 = {0.f,0.f,0.f,0.f};
        if (j < BB) {
            v0 = *(const float4*)&feats[(size_t)j * DD + k0];
            v1 = *(const float4*)&feats[(size_t)j * DD + k0 + 4];
        } else if (j < NN) {
            v0 = *(const float4*)&ctrs[(size_t)(j - BB) * DD + k0];
            v1 = *(const float4*)&ctrs[(size_t)(j - BB) * DD + k0 + 4];
        }
        short8 o;
        o[0]=f2bf(v0.x); o[1]=f2bf(v0.y); o[2]=f2bf(v0.z); o[3]=f2bf(v0.w);
        o[4]=f2bf(v1.x); o[5]=f2bf(v1.y); o[6]=f2bf(v1.z); o[7]=f2bf(v1.w);
        size_t offb = (size_t)((((j >> 4) * 4 + (quad >> 2)) * 64 + (quad & 3) * 16 + (j & 15)) * 8);
        *(short8*)&F2[offb] = o;
        return;
    }

    __shared__ int h[1024];
    h[tid] = 0;
    __syncthreads();
    for (int i = tid; i < BB; i += 1024) atomicAdd(&h[tgt[i]], 1);
    __syncthreads();

    cls[tid] = h[tid];                    // npos for rows of class tid

    for (int j = tid; j < NPAD; j += 1024) {
        if (j < NN) {
            int c = (j < BB) ? tgt[j] : (j - BB);
            int n = h[c] + 1;             // +1: the class center itself
            tcol[j] = c;
            rcp0[j] = 1.0f / (float)n;
            rcp1[j] = (n > 1) ? 1.0f / (float)(n - 1) : 0.0f;
        } else { tcol[j] = -2; rcp0[j] = 0.0f; rcp1[j] = 0.0f; }
    }
}

// one 16-col x 32-k fragment group (4 x 1KB coalesced loads)
static __device__ __forceinline__ void loadB(const unsigned short* __restrict__ F2,
                                             int j0, int lane8, short8 (&buf)[4]) {
#pragma unroll
    for (int ks = 0; ks < 4; ++ks)
        buf[ks] = *(const short8*)&F2[(size_t)(((j0 >> 4) * 4 + ks) * 512 + lane8)];
}

// 16 MFMAs: 64 rows x 16 cols x full K=128
static __device__ __forceinline__ void mfma16(const short8 (&af)[4][4], const short8 (&b)[4],
                                              f32x4 (&acc)[4]) {
    const f32x4 z4 = {0.f, 0.f, 0.f, 0.f};
#pragma unroll
    for (int fm = 0; fm < 4; ++fm)
        acc[fm] = __builtin_amdgcn_mfma_f32_16x16x32_bf16(af[0][fm], b[0], z4, 0, 0, 0);
#pragma unroll
    for (int ks = 1; ks < 4; ++ks)
#pragma unroll
        for (int fm = 0; fm < 4; ++fm)
            acc[fm] = __builtin_amdgcn_mfma_f32_16x16x32_bf16(
                af[ks][fm], b[ks], acc[fm], 0, 0, 0);
}

// fused mask epilogue: ~6 VALU + 1 trans per element
template<bool DIAG>
static __device__ __forceinline__ void epi16(const f32x4 (&acc)[4], float r0, float r1,
                                             int tj, int j0, int l15, int rowbase,
                                             const int (&ti)[16],
                                             float (&Sl)[16], float (&Pl)[16]) {
    const int col = j0 + l15;
#pragma unroll
    for (int fm = 0; fm < 4; ++fm)
#pragma unroll
        for (int q = 0; q < 4; ++q) {
            const int x = fm * 4 + q;
            float d = acc[fm][q];
            float l2 = fmaf(d, K2F, -K2F);
            float e = fexp2(l2);
            bool m = (tj == ti[x]);
            if (DIAG) {
                bool self = (col == rowbase + fm * 16 + q);
                if (self) { e = 0.f; m = false; }
            }
            float rw = m ? r1 : r0;
            Sl[x] = fmaf(e, rw, Sl[x]);       // padded cols: rcp=0
            Pl[x] += m ? d : 0.f;             // sum of masked raw dots
        }
}

__global__ __launch_bounds__(256, 2) void main_kernel(
    const unsigned short* __restrict__ F2, const int* __restrict__ tcol,
    const float* __restrict__ rcp0, const float* __restrict__ rcp1,
    float* __restrict__ S_part, float* __restrict__ P_part)
{
    const int tid  = threadIdx.x;
    const int lane = tid & 63;
    const int wave = tid >> 6;
    const int l15 = lane & 15, l4 = lane >> 4;
    const int lane8 = lane * 8;
    const int row0 = blockIdx.x * (4 * RBW) + wave * RBW;  // per-wave 64-row group
    const int split = blockIdx.y;
    const int cb = split * CPW;                  // SAME columns for all 4 waves -> L1 reuse
    const int rowbase = row0 + l4 * 4;

    // A fragments straight from global (this wave's 64 rows), persistent
    short8 af[4][4];                             // [ks][fm]
#pragma unroll
    for (int fm = 0; fm < 4; ++fm)
#pragma unroll
        for (int ks = 0; ks < 4; ++ks)
            af[ks][fm] = *(const short8*)&F2[(size_t)((((row0 >> 4) + fm) * 4 + ks) * 512 + lane8)];

    int ti[16];                                  // row classes for this lane's 16 rows
#pragma unroll
    for (int fm = 0; fm < 4; ++fm)
#pragma unroll
        for (int q = 0; q < 4; ++q)
            ti[fm * 4 + q] = tcol[rowbase + fm * 16 + q];

    float Sl[16], Pl[16];
#pragma unroll
    for (int x = 0; x < 16; ++x) { Sl[x] = 0.f; Pl[x] = 0.f; }

    // 3-buffer rotation, 2-deep prefetch (all names compile-time indexed)
    short8 b0[4], b1[4], b2[4];
    float r0A, r0B, r0C, r1A, r1B, r1C;
    int tjA, tjB, tjC;
    loadB(F2, cb, lane8, b0);
    r0A = rcp0[cb + l15]; r1A = rcp1[cb + l15]; tjA = tcol[cb + l15];
    loadB(F2, cb + 16, lane8, b1);
    r0B = rcp0[cb + 16 + l15]; r1B = rcp1[cb + 16 + l15]; tjB = tcol[cb + 16 + l15];

#pragma unroll 1
    for (int tt = 0; tt < NT; tt += 3) {
        {
            if (tt + 2 < NT) {
                int j = cb + (tt + 2) * 16;
                loadB(F2, j, lane8, b2);
                r0C = rcp0[j + l15]; r1C = rcp1[j + l15]; tjC = tcol[j + l15];
            }
            const int j0 = cb + tt * 16;
            f32x4 acc[4];
            mfma16(af, b0, acc);
            if ((unsigned)(j0 - row0) < 64u)
                epi16<true >(acc, r0A, r1A, tjA, j0, l15, rowbase, ti, Sl, Pl);
            else
                epi16<false>(acc, r0A, r1A, tjA, j0, l15, rowbase, ti, Sl, Pl);
        }
        {
            if (tt + 3 < NT) {
                int j = cb + (tt + 3) * 16;
                loadB(F2, j, lane8, b0);
                r0A = rcp0[j + l15]; r1A = rcp1[j + l15]; tjA = tcol[j + l15];
            }
            const int j0 = cb + (tt + 1) * 16;
            f32x4 acc[4];
            mfma16(af, b1, acc);
            if ((unsigned)(j0 - row0) < 64u)
                epi16<true >(acc, r0B, r1B, tjB, j0, l15, rowbase, ti, Sl, Pl);
            else
                epi16<false>(acc, r0B, r1B, tjB, j0, l15, rowbase, ti, Sl, Pl);
        }
        {
            if (tt + 4 < NT) {
                int j = cb + (tt + 4) * 16;
                loadB(F2, j, lane8, b1);
                r0B = rcp0[j + l15]; r1B = rcp1[j + l15]; tjB = tcol[j + l15];
            }
            const int j0 = cb + (tt + 2) * 16;
            f32x4 acc[4];
            mfma16(af, b2, acc);
            if ((unsigned)(j0 - row0) < 64u)
                epi16<true >(acc, r0C, r1C, tjC, j0, l15, rowbase, ti, Sl, Pl);
            else
                epi16<false>(acc, r0C, r1C, tjC, j0, l15, rowbase, ti, Sl, Pl);
        }
    }

    // 16-lane column reduce (tree); waves own disjoint rows -> direct write, no barrier
#pragma unroll
    for (int idx = 0; idx < 16; ++idx) {
        float S = Sl[idx], P = Pl[idx];
#pragma unroll
        for (int off = 1; off < 16; off <<= 1) {
            S += __shfl_xor(S, off, 64);
            P += __shfl_xor(P, off, 64);
        }
        if (l15 == 0) {
            int row = row0 + (idx >> 2) * 16 + l4 * 4 + (idx & 3);
            S_part[split * BB + row] = S;
            P_part[split * BB + row] = P;
        }
    }
}

// one block: combine split partials, per-row lp, mean, write scalar
__global__ __launch_bounds__(1024) void final_kernel(
    const int* __restrict__ tgt, const int* __restrict__ cls,
    const float* __restrict__ S_part, const float* __restrict__ P_part,
    float* __restrict__ out)
{
    const int tid = threadIdx.x;
    float lpsum = 0.f;
    for (int i = tid; i < BB; i += 1024) {
        float S = 0.f, P = 0.f;
#pragma unroll
        for (int s = 0; s < NSPLIT; ++s) {
            S += S_part[s * BB + i];
            P += P_part[s * BB + i];
        }
        const float npos = (float)cls[tgt[i]];
        lpsum += fmaf(K2F, P / npos, -K2F) - flog2(S);   // log2 units
    }
#pragma unroll
    for (int off = 1; off < 64; off <<= 1) lpsum += __shfl_xor(lpsum, off, 64);
    __shared__ float wsum[16];
    if ((tid & 63) == 0) wsum[tid >> 6] = lpsum;
    __syncthreads();
    if (tid == 0) {
        float t = 0.f;
#pragma unroll
        for (int w = 0; w < 16; ++w) t += wsum[w];
        out[0] = -0.6931471805599453f * (t / (float)BB);   // ln2 * mean, negated
    }
}

extern "C" void kernel_launch(void* const* d_in, const int* in_sizes, int n_in,
                              void* d_out, int out_size, void* d_ws, size_t ws_size,
                              hipStream_t stream) {
    const float* ctrs  = (const float*)d_in[0];   // centers1 [1000,128]
    const float* feats = (const float*)d_in[1];   // features [8192,128]
    const int*   tgt   = (const int*)d_in[2];     // targets  [8192] int32
    float* out = (float*)d_out;
    float* ws  = (float*)d_ws;

    int*   cls  = (int*)(ws + WS_CLS);
    int*   tcol = (int*)(ws + WS_TCOL);
    float* rcp0 = ws + WS_RCP0;
    float* rcp1 = ws + WS_RCP1;
    float* Sp   = ws + WS_SPART;
    float* Pp   = ws + WS_PPART;
    unsigned short* F2 = (unsigned short*)(ws + WS_F2);

    prep_kernel<<<dim3(145), dim3(1024), 0, stream>>>(feats, ctrs, tgt, F2, cls, tcol, rcp0, rcp1);
    main_kernel<<<dim3(BB / (4 * RBW), NSPLIT), dim3(256), 0, stream>>>(F2, tcol, rcp0, rcp1, Sp, Pp);
    final_kernel<<<dim3(1), dim3(1024), 0, stream>>>(tgt, cls, Sp, Pp, out);
}

// Round 15
// 45.149 us; speedup vs baseline: 1.2199x; 1.2199x over previous
//
#include <hip/hip_runtime.h>
#include <math.h>

typedef __attribute__((ext_vector_type(8))) short short8;
typedef __attribute__((ext_vector_type(4))) float f32x4;

#define BB 8192      // batch
#define CC 1000      // classes
#define NN 9192      // B + C real columns
#define NPAD 9216    // padded
#define DD 128       // feature dim
#define RBW 64       // rows per WAVE (block covers 4*64 = 256 rows)
#define NSPLIT 16    // column splits (blockIdx.y) -> grid 32x16 = 512 = 2 blocks/CU
#define CPW 576      // columns per block = 9216/NSPLIT (shared by all 4 waves)
#define NT 36        // 16-col chunks (divisible by 3 for 3-buffer rotation)
#define K2F 14.426950408889634f   // (1/T) * log2(e)

// ---- workspace layout (float offsets) ----
#define WS_CLS   0        // [1024] int batch histogram
#define WS_TCOL  1024     // [9216] int per-column class
#define WS_RCP0  10240    // [9216] 1/cnt
#define WS_RCP1  19456    // [9216] 1/(cnt-1)
#define WS_SPART 28672    // [8192*16]  S partials, row-major [row][split]
#define WS_PPART 159744   // [8192*16]  P partials, row-major [row][split]
#define WS_F2    290816   // fragment-major bf16 [9216*128]
#define WS_BS    880640   // [32] final1 block partials

static __device__ __forceinline__ unsigned short f2bf(float x) {
    unsigned int b = __float_as_uint(x);
    unsigned int r = (b + 0x7FFFu + ((b >> 16) & 1u)) >> 16;   // RNE
    return (unsigned short)r;
}
static __device__ __forceinline__ float fexp2(float x) {
    float r; asm("v_exp_f32 %0, %1" : "=v"(r) : "v"(x)); return r;
}
static __device__ __forceinline__ float flog2(float x) {
    float r; asm("v_log_f32 %0, %1" : "=v"(r) : "v"(x)); return r;
}

// ---- fused prep: blocks 0..143 convert fp32 -> fragment-major bf16;
//      block 144: histogram + per-column class/weight tables ----
__global__ __launch_bounds__(1024) void prep_kernel(
    const float* __restrict__ feats, const float* __restrict__ ctrs,
    const int* __restrict__ tgt, unsigned short* __restrict__ F2,
    int* __restrict__ cls, int* __restrict__ tcol,
    float* __restrict__ rcp0, float* __restrict__ rcp1)
{
    const int tid = threadIdx.x;
    if (blockIdx.x < 144) {
        // cvt: one short8-unit per thread.  F2 fragment-major: 16B unit
        // u = (j16*4 + ks)*64 + l4*16 + l15 holds (col j=j16*16+l15, k=ks*32+l4*8..+8)
        int u = blockIdx.x * 1024 + tid;          // < 147456 = NPAD*16
        int j = u >> 4, quad = u & 15;
        int k0 = quad * 8;
        float4 v0 = {0.f,0.f,0.f,0.f}, v1 = {0.f,0.f,0.f,0.f};
        if (j < BB) {
            v0 = *(const float4*)&feats[(size_t)j * DD + k0];
            v1 = *(const float4*)&feats[(size_t)j * DD + k0 + 4];
        } else if (j < NN) {
            v0 = *(const float4*)&ctrs[(size_t)(j - BB) * DD + k0];
            v1 = *(const float4*)&ctrs[(size_t)(j - BB) * DD + k0 + 4];
        }
        short8 o;
        o[0]=f2bf(v0.x); o[1]=f2bf(v0.y); o[2]=f2bf(v0.z); o[3]=f2bf(v0.w);
        o[4]=f2bf(v1.x); o[5]=f2bf(v1.y); o[6]=f2bf(v1.z); o[7]=f2bf(v1.w);
        size_t offb = (size_t)((((j >> 4) * 4 + (quad >> 2)) * 64 + (quad & 3) * 16 + (j & 15)) * 8);
        *(short8*)&F2[offb] = o;
        return;
    }

    __shared__ int h[1024];
    h[tid] = 0;
    __syncthreads();
    for (int i = tid; i < BB; i += 1024) atomicAdd(&h[tgt[i]], 1);
    __syncthreads();

    cls[tid] = h[tid];                    // npos for rows of class tid

    for (int j = tid; j < NPAD; j += 1024) {
        if (j < NN) {
            int c = (j < BB) ? tgt[j] : (j - BB);
            int n = h[c] + 1;             // +1: the class center itself
            tcol[j] = c;
            rcp0[j] = 1.0f / (float)n;
            rcp1[j] = (n > 1) ? 1.0f / (float)(n - 1) : 0.0f;
        } else { tcol[j] = -2; rcp0[j] = 0.0f; rcp1[j] = 0.0f; }
    }
}

// one 16-col x 32-k fragment group (4 x 1KB coalesced loads)
static __device__ __forceinline__ void loadB(const unsigned short* __restrict__ F2,
                                             int j0, int lane8, short8 (&buf)[4]) {
#pragma unroll
    for (int ks = 0; ks < 4; ++ks)
        buf[ks] = *(const short8*)&F2[(size_t)(((j0 >> 4) * 4 + ks) * 512 + lane8)];
}

// 16 MFMAs: 64 rows x 16 cols x full K=128
static __device__ __forceinline__ void mfma16(const short8 (&af)[4][4], const short8 (&b)[4],
                                              f32x4 (&acc)[4]) {
    const f32x4 z4 = {0.f, 0.f, 0.f, 0.f};
#pragma unroll
    for (int fm = 0; fm < 4; ++fm)
        acc[fm] = __builtin_amdgcn_mfma_f32_16x16x32_bf16(af[0][fm], b[0], z4, 0, 0, 0);
#pragma unroll
    for (int ks = 1; ks < 4; ++ks)
#pragma unroll
        for (int fm = 0; fm < 4; ++fm)
            acc[fm] = __builtin_amdgcn_mfma_f32_16x16x32_bf16(
                af[ks][fm], b[ks], acc[fm], 0, 0, 0);
}

// fused mask epilogue: ~6 VALU + 1 trans per element
template<bool DIAG>
static __device__ __forceinline__ void epi16(const f32x4 (&acc)[4], float r0, float r1,
                                             int tj, int j0, int l15, int rowbase,
                                             const int (&ti)[16],
                                             float (&Sl)[16], float (&Pl)[16]) {
    const int col = j0 + l15;
#pragma unroll
    for (int fm = 0; fm < 4; ++fm)
#pragma unroll
        for (int q = 0; q < 4; ++q) {
            const int x = fm * 4 + q;
            float d = acc[fm][q];
            float l2 = fmaf(d, K2F, -K2F);
            float e = fexp2(l2);
            bool m = (tj == ti[x]);
            if (DIAG) {
                bool self = (col == rowbase + fm * 16 + q);
                if (self) { e = 0.f; m = false; }
            }
            float rw = m ? r1 : r0;
            Sl[x] = fmaf(e, rw, Sl[x]);       // padded cols: rcp=0
            Pl[x] += m ? d : 0.f;             // sum of masked raw dots
        }
}

__global__ __launch_bounds__(256, 2) void main_kernel(
    const unsigned short* __restrict__ F2, const int* __restrict__ tcol,
    const float* __restrict__ rcp0, const float* __restrict__ rcp1,
    float* __restrict__ S_part, float* __restrict__ P_part)
{
    const int tid  = threadIdx.x;
    const int lane = tid & 63;
    const int wave = tid >> 6;
    const int l15 = lane & 15, l4 = lane >> 4;
    const int lane8 = lane * 8;
    const int row0 = blockIdx.x * (4 * RBW) + wave * RBW;  // per-wave 64-row group
    const int split = blockIdx.y;
    const int cb = split * CPW;                  // SAME columns for all 4 waves -> L1 reuse
    const int rowbase = row0 + l4 * 4;

    // A fragments straight from global (this wave's 64 rows), persistent
    short8 af[4][4];                             // [ks][fm]
#pragma unroll
    for (int fm = 0; fm < 4; ++fm)
#pragma unroll
        for (int ks = 0; ks < 4; ++ks)
            af[ks][fm] = *(const short8*)&F2[(size_t)((((row0 >> 4) + fm) * 4 + ks) * 512 + lane8)];

    int ti[16];                                  // row classes for this lane's 16 rows
#pragma unroll
    for (int fm = 0; fm < 4; ++fm)
#pragma unroll
        for (int q = 0; q < 4; ++q)
            ti[fm * 4 + q] = tcol[rowbase + fm * 16 + q];

    float Sl[16], Pl[16];
#pragma unroll
    for (int x = 0; x < 16; ++x) { Sl[x] = 0.f; Pl[x] = 0.f; }

    // 3-buffer rotation, 2-deep prefetch (all names compile-time indexed)
    short8 b0[4], b1[4], b2[4];
    float r0A, r0B, r0C, r1A, r1B, r1C;
    int tjA, tjB, tjC;
    loadB(F2, cb, lane8, b0);
    r0A = rcp0[cb + l15]; r1A = rcp1[cb + l15]; tjA = tcol[cb + l15];
    loadB(F2, cb + 16, lane8, b1);
    r0B = rcp0[cb + 16 + l15]; r1B = rcp1[cb + 16 + l15]; tjB = tcol[cb + 16 + l15];

#pragma unroll 1
    for (int tt = 0; tt < NT; tt += 3) {
        {
            if (tt + 2 < NT) {
                int j = cb + (tt + 2) * 16;
                loadB(F2, j, lane8, b2);
                r0C = rcp0[j + l15]; r1C = rcp1[j + l15]; tjC = tcol[j + l15];
            }
            const int j0 = cb + tt * 16;
            f32x4 acc[4];
            mfma16(af, b0, acc);
            if ((unsigned)(j0 - row0) < 64u)
                epi16<true >(acc, r0A, r1A, tjA, j0, l15, rowbase, ti, Sl, Pl);
            else
                epi16<false>(acc, r0A, r1A, tjA, j0, l15, rowbase, ti, Sl, Pl);
        }
        {
            if (tt + 3 < NT) {
                int j = cb + (tt + 3) * 16;
                loadB(F2, j, lane8, b0);
                r0A = rcp0[j + l15]; r1A = rcp1[j + l15]; tjA = tcol[j + l15];
            }
            const int j0 = cb + (tt + 1) * 16;
            f32x4 acc[4];
            mfma16(af, b1, acc);
            if ((unsigned)(j0 - row0) < 64u)
                epi16<true >(acc, r0B, r1B, tjB, j0, l15, rowbase, ti, Sl, Pl);
            else
                epi16<false>(acc, r0B, r1B, tjB, j0, l15, rowbase, ti, Sl, Pl);
        }
        {
            if (tt + 4 < NT) {
                int j = cb + (tt + 4) * 16;
                loadB(F2, j, lane8, b1);
                r0B = rcp0[j + l15]; r1B = rcp1[j + l15]; tjB = tcol[j + l15];
            }
            const int j0 = cb + (tt + 2) * 16;
            f32x4 acc[4];
            mfma16(af, b2, acc);
            if ((unsigned)(j0 - row0) < 64u)
                epi16<true >(acc, r0C, r1C, tjC, j0, l15, rowbase, ti, Sl, Pl);
            else
                epi16<false>(acc, r0C, r1C, tjC, j0, l15, rowbase, ti, Sl, Pl);
        }
    }

    // 16-lane column reduce (tree); waves own disjoint rows -> direct write, no barrier
    // partials stored row-major [row][split] so final1 reads are contiguous per row
#pragma unroll
    for (int idx = 0; idx < 16; ++idx) {
        float S = Sl[idx], P = Pl[idx];
#pragma unroll
        for (int off = 1; off < 16; off <<= 1) {
            S += __shfl_xor(S, off, 64);
            P += __shfl_xor(P, off, 64);
        }
        if (l15 == 0) {
            int row = row0 + (idx >> 2) * 16 + l4 * 4 + (idx & 3);
            S_part[(size_t)row * NSPLIT + split] = S;
            P_part[(size_t)row * NSPLIT + split] = P;
        }
    }
}

// 32 blocks x 256 threads: one row per thread, coalesced [row][split] reads
__global__ __launch_bounds__(256) void final1_kernel(
    const int* __restrict__ tgt, const int* __restrict__ cls,
    const float* __restrict__ S_part, const float* __restrict__ P_part,
    float* __restrict__ bs)
{
    const int tid = threadIdx.x;
    const int i = blockIdx.x * 256 + tid;
    float S = 0.f, P = 0.f;
    const float4* sp = (const float4*)&S_part[(size_t)i * NSPLIT];
    const float4* pp = (const float4*)&P_part[(size_t)i * NSPLIT];
#pragma unroll
    for (int q = 0; q < NSPLIT / 4; ++q) {
        float4 a = sp[q]; S += (a.x + a.y) + (a.z + a.w);
        float4 b = pp[q]; P += (b.x + b.y) + (b.z + b.w);
    }
    const float npos = (float)cls[tgt[i]];
    float lp = fmaf(K2F, P / npos, -K2F) - flog2(S);   // log2 units

#pragma unroll
    for (int off = 1; off < 64; off <<= 1) lp += __shfl_xor(lp, off, 64);
    __shared__ float wsum[4];
    if ((tid & 63) == 0) wsum[tid >> 6] = lp;
    __syncthreads();
    if (tid == 0) bs[blockIdx.x] = wsum[0] + wsum[1] + wsum[2] + wsum[3];
}

__global__ void final2_kernel(const float* __restrict__ bs, float* __restrict__ out) {
    const int t = threadIdx.x;   // 64 threads
    float v = (t < 32) ? bs[t] : 0.f;
#pragma unroll
    for (int off = 1; off < 64; off <<= 1) v += __shfl_xor(v, off, 64);
    if (t == 0) out[0] = -0.6931471805599453f * (v / (float)BB);   // ln2 * mean, negated
}

extern "C" void kernel_launch(void* const* d_in, const int* in_sizes, int n_in,
                              void* d_out, int out_size, void* d_ws, size_t ws_size,
                              hipStream_t stream) {
    const float* ctrs  = (const float*)d_in[0];   // centers1 [1000,128]
    const float* feats = (const float*)d_in[1];   // features [8192,128]
    const int*   tgt   = (const int*)d_in[2];     // targets  [8192] int32
    float* out = (float*)d_out;
    float* ws  = (float*)d_ws;

    int*   cls  = (int*)(ws + WS_CLS);
    int*   tcol = (int*)(ws + WS_TCOL);
    float* rcp0 = ws + WS_RCP0;
    float* rcp1 = ws + WS_RCP1;
    float* Sp   = ws + WS_SPART;
    float* Pp   = ws + WS_PPART;
    float* bs   = ws + WS_BS;
    unsigned short* F2 = (unsigned short*)(ws + WS_F2);

    prep_kernel<<<dim3(145), dim3(1024), 0, stream>>>(feats, ctrs, tgt, F2, cls, tcol, rcp0, rcp1);
    main_kernel<<<dim3(BB / (4 * RBW), NSPLIT), dim3(256), 0, stream>>>(F2, tcol, rcp0, rcp1, Sp, Pp);
    final1_kernel<<<dim3(BB / 256), dim3(256), 0, stream>>>(tgt, cls, Sp, Pp, bs);
    final2_kernel<<<dim3(1), dim3(64), 0, stream>>>(bs, out);
}